// Round 1
// baseline (168.030 us; speedup 1.0000x reference)
//
#include <hip/hip_runtime.h>

#define FD 20
#define DD 64

#define GA 64     // gram partials for A (users)  = GAB blocks * 4 waves
#define GB 128    // gram partials for B (items)  = GBB blocks * 4 waves
#define GAB 16    // gram blocks for A
#define GBB 32    // gram blocks for B
#define POSB 2048 // pos blocks in fused mid kernel
#define NEGB 64   // neg reduce blocks (one Gram row each)

typedef float float4v __attribute__((ext_vector_type(4)));
typedef unsigned short ushort4v __attribute__((ext_vector_type(4)));
typedef unsigned short ushort8v __attribute__((ext_vector_type(8)));
typedef short short8v __attribute__((ext_vector_type(8)));

__device__ __forceinline__ unsigned short f2bf(float f) {
    unsigned u = __float_as_uint(f);
    unsigned r = u + 0x7fffu + ((u >> 16) & 1u);   // round-to-nearest-even
    return (unsigned short)(r >> 16);
}
__device__ __forceinline__ float bf2f(unsigned short h) {
    return __uint_as_float((unsigned)h << 16);
}

// ---------------------------------------------------------------------------
// Kernel 0: fp32 -> fp8 e4m3 (OCP) conversion of both embedding tables via
// HW v_cvt_pk_fp8_f32, plus zero-init of d_out.
// ---------------------------------------------------------------------------
__global__ __launch_bounds__(256) void conv_kernel(
    const float* __restrict__ ue, const float* __restrict__ ie,
    unsigned int* __restrict__ u8, unsigned int* __restrict__ i8,
    int n4, float* __restrict__ out, int out_size)
{
    int i = blockIdx.x * blockDim.x + threadIdx.x;
    if (i < out_size) out[i] = 0.0f;
    if (i >= 2 * n4) return;
    const float4v* src; unsigned int* dst; int k;
    if (i < n4) { src = (const float4v*)ue; dst = u8; k = i; }
    else        { src = (const float4v*)ie; dst = i8; k = i - n4; }
    float4v v = src[k];
    unsigned int p = 0;
    p = __builtin_amdgcn_cvt_pk_fp8_f32(v.x, v.y, p, false);  // bytes 0,1
    p = __builtin_amdgcn_cvt_pk_fp8_f32(v.z, v.w, p, true);   // bytes 2,3
    dst[k] = p;
}

// ---------------------------------------------------------------------------
// Kernel 1: per-entity FM terms, fp8 gathers, bf16 p/q output. (unchanged)
// ---------------------------------------------------------------------------
__global__ __launch_bounds__(256, 4) void entity_kernel(
    const unsigned char* __restrict__ user_f8,
    const unsigned char* __restrict__ item_f8,
    const float* __restrict__ w_user, const float* __restrict__ w_item,
    const float* __restrict__ bias, const float* __restrict__ h1,
    const int* __restrict__ ufeat, const int* __restrict__ ifeat,
    unsigned short* __restrict__ p_bf, float* __restrict__ su,
    unsigned short* __restrict__ q_bf, float* __restrict__ sv,
    int U, int V)
{
    int wid  = (int)((blockIdx.x * blockDim.x + threadIdx.x) >> 6);
    int lane = threadIdx.x & 63;
    if (wid >= U + V) return;

    const unsigned char* emb; const float* wv; const int* fidx; float extra;
    unsigned short* srow; float* sc;
    if (wid < U) {
        emb = user_f8; wv = w_user; fidx = ufeat + (size_t)wid * FD;
        extra = bias[0]; srow = p_bf + (size_t)wid * DD; sc = su + wid;
    } else {
        int m = wid - U;
        emb = item_f8; wv = w_item; fidx = ifeat + (size_t)m * FD;
        extra = 0.0f; srow = q_bf + (size_t)m * DD; sc = sv + m;
    }

    int myidx = 0; float myw = 0.0f;
    if (lane < FD) {
        myidx = fidx[lane];
        myw   = wv[myidx];
    }

    int grp = lane >> 4;     // 0..3: feature group
    int c   = lane & 15;     // 4-dim chunk within the 64-dim row

    int fx[5];
#pragma unroll
    for (int i = 0; i < 5; ++i)
        fx[i] = __shfl(myidx, grp + 4 * i, 64);

    unsigned int hw[5];
#pragma unroll
    for (int i = 0; i < 5; ++i)
        hw[i] = *((const unsigned int*)(emb + (size_t)fx[i] * DD) + c);

    float4v s4 = (float4v)0.0f, ss4 = (float4v)0.0f;
#pragma unroll
    for (int i = 0; i < 5; ++i) {
        float4v g;
        g.x = __builtin_amdgcn_cvt_f32_fp8(hw[i], 0);
        g.y = __builtin_amdgcn_cvt_f32_fp8(hw[i], 1);
        g.z = __builtin_amdgcn_cvt_f32_fp8(hw[i], 2);
        g.w = __builtin_amdgcn_cvt_f32_fp8(hw[i], 3);
        s4 += g; ss4 += g * g;
    }

#pragma unroll
    for (int off = 16; off <= 32; off <<= 1) {
        float4v t, u;
        t.x = __shfl_xor(s4.x,  off, 64); t.y = __shfl_xor(s4.y,  off, 64);
        t.z = __shfl_xor(s4.z,  off, 64); t.w = __shfl_xor(s4.w,  off, 64);
        u.x = __shfl_xor(ss4.x, off, 64); u.y = __shfl_xor(ss4.y, off, 64);
        u.z = __shfl_xor(ss4.z, off, 64); u.w = __shfl_xor(ss4.w, off, 64);
        s4 += t; ss4 += u;
    }

    float part = myw;
    if (grp == 0) {
        float4v h14 = *(const float4v*)(h1 + c * 4);
        float4v bi4 = 0.5f * (s4 * s4 - ss4);
        part += bi4.x*h14.x + bi4.y*h14.y + bi4.z*h14.z + bi4.w*h14.w;
        ushort4v o;
        o.x = f2bf(s4.x); o.y = f2bf(s4.y); o.z = f2bf(s4.z); o.w = f2bf(s4.w);
        *(ushort4v*)(srow + c * 4) = o;
    }

#pragma unroll
    for (int off = 1; off <= 32; off <<= 1)
        part += __shfl_xor(part, off, 64);

    if (lane == 0) *sc = part + extra;
}

// ---------------------------------------------------------------------------
// MFMA Gram partial: one WAVE per 64-row tile (private 8KB bf16 LDS tile,
// no barriers). G = M^T M: A-frag == B-frag per 16-dim block, so each K=32
// chunk is 4 fragment loads + 10 MFMAs (upper-triangle tiles only).
// LDS rows are 16B-chunk XOR-swizzled so the stride-128B ds_read_u16
// fragment reads hit all 32 banks (quarters get distinct even rotations).
// C/D layout (m89-verified): col = lane&15, row = (lane>>4)*4 + reg.
// ---------------------------------------------------------------------------
__device__ __forceinline__ void gram_block_mfma(
    const unsigned short* __restrict__ M, int nrows, int gwid, int nw,
    float* __restrict__ Gpart, unsigned short* __restrict__ sm)
{
    int lane = threadIdx.x & 63;
    int q = lane >> 4;       // lane quarter
    int c = lane & 15;       // dim-within-block / output col

    float4v acc[10];
#pragma unroll
    for (int t = 0; t < 10; ++t) acc[t] = (float4v)0.0f;

    int ntiles = (nrows + 63) >> 6;
    for (int tt = gwid; tt < ntiles; tt += nw) {
        int row0 = tt << 6;
        // ---- stage 64x64 bf16 tile; swizzle 16B chunk index by row ----
#pragma unroll
        for (int p = 0; p < 8; ++p) {
            int r  = p * 8 + (lane >> 3);         // row 0..63  (r>>3 == p)
            int ch = lane & 7;                    // 16B chunk 0..7
            ushort8v hv = (ushort8v)0;
            if (row0 + r < nrows)
                hv = *(const ushort8v*)(M + (size_t)(row0 + r) * DD + ch * 8);
            int X = (p & 3) << 1;                 // X(r) = ((r>>3)&3)<<1
            *(ushort8v*)(sm + r * 64 + ((ch ^ X) << 3)) = hv;
        }
        // ---- two K=32 chunks ----
#pragma unroll
        for (int kb2 = 0; kb2 < 2; ++kb2) {
            int k0 = kb2 * 32 + q * 8;            // this quarter's k base
            int X  = q << 1;                      // ((k0>>3)&3)<<1
            const unsigned short* rb = sm + k0 * 64 + (c & 7);
            short8v f[4];
#pragma unroll
            for (int Db = 0; Db < 4; ++Db) {
                int chunk = (Db * 2 + (c >> 3)) ^ X;
                const unsigned short* b = rb + chunk * 8;
                short8v fv;
#pragma unroll
                for (int j = 0; j < 8; ++j)
                    fv[j] = (short)b[j * 64];     // ds_read_u16, offset j*128B
                f[Db] = fv;
            }
#define MM(i_, j_, t_) acc[t_] = __builtin_amdgcn_mfma_f32_16x16x32_bf16(f[i_], f[j_], acc[t_], 0, 0, 0);
            MM(0,0,0) MM(0,1,1) MM(0,2,2) MM(0,3,3) MM(1,1,4)
            MM(1,2,5) MM(1,3,6) MM(2,2,7) MM(2,3,8) MM(3,3,9)
#undef MM
        }
    }

    // ---- epilogue: write this wave's 64x64 partial, upper tiles only ----
    float* out = Gpart + (size_t)gwid * (DD * DD);
#define ST(i_, j_, t_)                                                     \
    {                                                                      \
        for (int rg = 0; rg < 4; ++rg)                                     \
            out[(i_ * 16 + q * 4 + rg) * DD + j_ * 16 + c] = acc[t_][rg];  \
    }
    ST(0,0,0) ST(0,1,1) ST(0,2,2) ST(0,3,3) ST(1,1,4)
    ST(1,2,5) ST(1,3,6) ST(2,2,7) ST(2,3,8) ST(3,3,9)
#undef ST
}

// ---------------------------------------------------------------------------
// Kernel 2 (fused): blocks [0,GAB) Gram-A, [GAB,GAB+GBB) Gram-B,
// [GAB+GBB, +POSB) pos pairs. Pos part unchanged.
// ---------------------------------------------------------------------------
__global__ __launch_bounds__(256) void mid_kernel(
    const unsigned short* __restrict__ p_bf, int U, float* __restrict__ PA,
    const unsigned short* __restrict__ q_bf, int V, float* __restrict__ PB,
    const float* __restrict__ su, const float* __restrict__ sv,
    const float* __restrict__ h2,
    const int* __restrict__ pu, const int* __restrict__ pi,
    int P, float* __restrict__ posPart)
{
    __shared__ unsigned short gtiles[4][64 * 64];   // 4 waves x 8KB
    __shared__ float red[4];
    int w = threadIdx.x >> 6;

    if (blockIdx.x < GAB) {
        gram_block_mfma(p_bf, U, blockIdx.x * 4 + w, GA, PA, gtiles[w]);
        return;
    }
    if (blockIdx.x < GAB + GBB) {
        gram_block_mfma(q_bf, V, (blockIdx.x - GAB) * 4 + w, GB, PB, gtiles[w]);
        return;
    }

    // ---- positive-pair part ----
    int lane = threadIdx.x & 63;
    int sl   = lane & 15;
    int sub  = lane >> 4;
    int pb   = blockIdx.x - (GAB + GBB);
    int wId  = pb * 4 + (threadIdx.x >> 6);
    const int NW = POSB * 4;                 // 8192 waves

    float4v h2v = *(const float4v*)(h2 + sl * 4);

    int pid0 = wId * 4 + sub;                // [0, 32768)
    int pid1 = pid0 + NW * 4;                // [32768, 65536)
    bool ok0 = pid0 < P, ok1 = pid1 < P;

    int u0 = 0, v0 = 0, u1 = 0, v1 = 0;
    if (ok0) { u0 = pu[pid0]; v0 = pi[pid0]; }
    if (ok1) { u1 = pu[pid1]; v1 = pi[pid1]; }

    ushort4v ph0 = (ushort4v)0, qh0 = (ushort4v)0;
    ushort4v ph1 = (ushort4v)0, qh1 = (ushort4v)0;
    if (ok0) {
        ph0 = *(const ushort4v*)(p_bf + (size_t)u0 * DD + sl * 4);
        qh0 = *(const ushort4v*)(q_bf + (size_t)v0 * DD + sl * 4);
    }
    if (ok1) {
        ph1 = *(const ushort4v*)(p_bf + (size_t)u1 * DD + sl * 4);
        qh1 = *(const ushort4v*)(q_bf + (size_t)v1 * DD + sl * 4);
    }

    float d0 = bf2f(ph0.x)*bf2f(qh0.x)*h2v.x + bf2f(ph0.y)*bf2f(qh0.y)*h2v.y
             + bf2f(ph0.z)*bf2f(qh0.z)*h2v.z + bf2f(ph0.w)*bf2f(qh0.w)*h2v.w;
    float d1 = bf2f(ph1.x)*bf2f(qh1.x)*h2v.x + bf2f(ph1.y)*bf2f(qh1.y)*h2v.y
             + bf2f(ph1.z)*bf2f(qh1.z)*h2v.z + bf2f(ph1.w)*bf2f(qh1.w)*h2v.w;
#pragma unroll
    for (int off = 1; off < 16; off <<= 1) {
        d0 += __shfl_xor(d0, off, 64);
        d1 += __shfl_xor(d1, off, 64);
    }

    float acc = 0.0f;
    if (sl == 0) {
        if (ok0) { float y = d0 + su[u0] + sv[v0]; acc += 0.5f * y * y - 2.0f * y; }
        if (ok1) { float y = d1 + su[u1] + sv[v1]; acc += 0.5f * y * y - 2.0f * y; }
    }
    acc += __shfl_xor(acc, 16, 64);
    acc += __shfl_xor(acc, 32, 64);
    if (lane == 0) red[threadIdx.x >> 6] = acc;
    __syncthreads();
    if (threadIdx.x == 0)
        posPart[pb] = red[0] + red[1] + red[2] + red[3];
}

// ---------------------------------------------------------------------------
// Kernel 3: reduce gram partials -> negative term, plus pos partials.
// Gram partials now hold only upper-triangle 16x16 tiles; G is symmetric,
// so entries in lower tiles are read from the mirrored position.
// ---------------------------------------------------------------------------
__global__ __launch_bounds__(256) void neg_reduce_kernel(
    const float* __restrict__ PA, const float* __restrict__ PB,
    const float* __restrict__ h2, const float* __restrict__ posPart,
    float* __restrict__ out)
{
    __shared__ float sA[4][64], sB[4][64];
    __shared__ float sPos;
    int t  = threadIdx.x;
    int l  = t & 63;
    int ch = t >> 6;                       // k-chunk 0..3
    int i  = blockIdx.x;                   // Gram row
    int e  = ((i >> 4) <= (l >> 4)) ? (i * 64 + l) : (l * 64 + i);

    float a = 0.0f, b = 0.0f;
#pragma unroll
    for (int k = 0; k < GA / 4; ++k)       // 16 loads
        a += PA[(size_t)(ch * (GA / 4) + k) * (DD * DD) + e];
#pragma unroll
    for (int k = 0; k < GB / 4; ++k)       // 32 loads
        b += PB[(size_t)(ch * (GB / 4) + k) * (DD * DD) + e];
    sA[ch][l] = a;
    sB[ch][l] = b;

    if (ch == 1) {                         // wave 1: fold 32 pos partials
        float p = (l < POSB / NEGB) ? posPart[blockIdx.x * (POSB / NEGB) + l] : 0.0f;
#pragma unroll
        for (int off = 1; off <= 32; off <<= 1)
            p += __shfl_xor(p, off, 64);
        if (l == 0) sPos = p;
    }
    __syncthreads();

    if (ch == 0) {
        float fa = sA[0][l] + sA[1][l] + sA[2][l] + sA[3][l];
        float fb = sB[0][l] + sB[1][l] + sB[2][l] + sB[3][l];
        float acc = 0.5f * h2[blockIdx.x] * h2[l] * fa * fb;
#pragma unroll
        for (int off = 1; off <= 32; off <<= 1)
            acc += __shfl_xor(acc, off, 64);
        if (l == 0)
            atomicAdd(out, acc + sPos);
    }
}

extern "C" void kernel_launch(void* const* d_in, const int* in_sizes, int n_in,
                              void* d_out, int out_size, void* d_ws, size_t ws_size,
                              hipStream_t stream)
{
    const float* user_emb = (const float*)d_in[0];
    const float* item_emb = (const float*)d_in[1];
    const float* w_user   = (const float*)d_in[2];
    const float* w_item   = (const float*)d_in[3];
    const float* bias     = (const float*)d_in[4];
    const float* h1       = (const float*)d_in[5];
    const float* h2       = (const float*)d_in[6];
    const int*   ufeat    = (const int*)d_in[7];
    const int*   ifeat    = (const int*)d_in[8];
    const int*   pu       = (const int*)d_in[9];
    const int*   pi       = (const int*)d_in[10];

    const int NF = in_sizes[0] / DD;
    const int U  = in_sizes[7] / FD;
    const int V  = in_sizes[8] / FD;
    const int P  = in_sizes[9];

    float* ws = (float*)d_ws;
    size_t off = 0;
    unsigned short* p_bf = (unsigned short*)(ws + off); off += (size_t)U * DD / 2;
    unsigned short* q_bf = (unsigned short*)(ws + off); off += (size_t)V * DD / 2;
    float* su   = ws + off; off += (size_t)U;          off = (off + 63) & ~(size_t)63;
    float* sv   = ws + off; off += (size_t)V;          off = (off + 63) & ~(size_t)63;
    float* PA   = ws + off; off += (size_t)GA * DD * DD;
    float* PB   = ws + off; off += (size_t)GB * DD * DD;
    float* posPart = ws + off; off += (size_t)POSB;    off = (off + 63) & ~(size_t)63;
    unsigned char* uf8 = (unsigned char*)(ws + off);   off += (size_t)NF * DD / 4;
    unsigned char* if8 = (unsigned char*)(ws + off);   off += (size_t)NF * DD / 4;

    float* out = (float*)d_out;

    int n4 = NF * DD / 4;
    conv_kernel<<<(2 * n4 + 255) / 256, 256, 0, stream>>>(
        user_emb, item_emb, (unsigned int*)uf8, (unsigned int*)if8,
        n4, out, out_size);

    int nent = U + V;
    entity_kernel<<<(nent + 3) / 4, 256, 0, stream>>>(
        uf8, if8, w_user, w_item, bias, h1,
        ufeat, ifeat, p_bf, su, q_bf, sv, U, V);

    mid_kernel<<<GAB + GBB + POSB, 256, 0, stream>>>(
        p_bf, U, PA, q_bf, V, PB, su, sv, h2, pu, pi, P, posPart);

    neg_reduce_kernel<<<NEGB, 256, 0, stream>>>(PA, PB, h2, posPart, out);
}

// Round 2
// 148.467 us; speedup vs baseline: 1.1318x; 1.1318x over previous
//
#include <hip/hip_runtime.h>

#define FD 20
#define DD 64

#define GA 64     // gram partials for A (users)  = GAB blocks * 4 waves
#define GB 128    // gram partials for B (items)  = GBB blocks * 4 waves
#define GAB 16    // gram blocks for A
#define GBB 32    // gram blocks for B
#define POSB 2048 // pos blocks in fused mid kernel
#define NEGB 64   // neg reduce blocks (one Gram row each)

typedef float float4v __attribute__((ext_vector_type(4)));
typedef unsigned short ushort4v __attribute__((ext_vector_type(4)));
typedef unsigned short ushort8v __attribute__((ext_vector_type(8)));
typedef short short8v __attribute__((ext_vector_type(8)));

__device__ __forceinline__ unsigned short f2bf(float f) {
    unsigned u = __float_as_uint(f);
    unsigned r = u + 0x7fffu + ((u >> 16) & 1u);   // round-to-nearest-even
    return (unsigned short)(r >> 16);
}
__device__ __forceinline__ float bf2f(unsigned short h) {
    return __uint_as_float((unsigned)h << 16);
}

// ---------------------------------------------------------------------------
// Kernel 0: fp32 -> fp8 e4m3 (OCP) conversion of both embedding tables via
// HW v_cvt_pk_fp8_f32, plus zero-init of d_out.
// ---------------------------------------------------------------------------
__global__ __launch_bounds__(256) void conv_kernel(
    const float* __restrict__ ue, const float* __restrict__ ie,
    unsigned int* __restrict__ u8, unsigned int* __restrict__ i8,
    int n4, float* __restrict__ out, int out_size)
{
    int i = blockIdx.x * blockDim.x + threadIdx.x;
    if (i < out_size) out[i] = 0.0f;
    if (i >= 2 * n4) return;
    const float4v* src; unsigned int* dst; int k;
    if (i < n4) { src = (const float4v*)ue; dst = u8; k = i; }
    else        { src = (const float4v*)ie; dst = i8; k = i - n4; }
    float4v v = src[k];
    unsigned int p = 0;
    p = __builtin_amdgcn_cvt_pk_fp8_f32(v.x, v.y, p, false);  // bytes 0,1
    p = __builtin_amdgcn_cvt_pk_fp8_f32(v.z, v.w, p, true);   // bytes 2,3
    dst[k] = p;
}

// ---------------------------------------------------------------------------
// Kernel 1: per-entity FM terms, fp8 gathers, bf16 p/q output. (unchanged)
// ---------------------------------------------------------------------------
__global__ __launch_bounds__(256, 4) void entity_kernel(
    const unsigned char* __restrict__ user_f8,
    const unsigned char* __restrict__ item_f8,
    const float* __restrict__ w_user, const float* __restrict__ w_item,
    const float* __restrict__ bias, const float* __restrict__ h1,
    const int* __restrict__ ufeat, const int* __restrict__ ifeat,
    unsigned short* __restrict__ p_bf, float* __restrict__ su,
    unsigned short* __restrict__ q_bf, float* __restrict__ sv,
    int U, int V)
{
    int wid  = (int)((blockIdx.x * blockDim.x + threadIdx.x) >> 6);
    int lane = threadIdx.x & 63;
    if (wid >= U + V) return;

    const unsigned char* emb; const float* wv; const int* fidx; float extra;
    unsigned short* srow; float* sc;
    if (wid < U) {
        emb = user_f8; wv = w_user; fidx = ufeat + (size_t)wid * FD;
        extra = bias[0]; srow = p_bf + (size_t)wid * DD; sc = su + wid;
    } else {
        int m = wid - U;
        emb = item_f8; wv = w_item; fidx = ifeat + (size_t)m * FD;
        extra = 0.0f; srow = q_bf + (size_t)m * DD; sc = sv + m;
    }

    int myidx = 0; float myw = 0.0f;
    if (lane < FD) {
        myidx = fidx[lane];
        myw   = wv[myidx];
    }

    int grp = lane >> 4;     // 0..3: feature group
    int c   = lane & 15;     // 4-dim chunk within the 64-dim row

    int fx[5];
#pragma unroll
    for (int i = 0; i < 5; ++i)
        fx[i] = __shfl(myidx, grp + 4 * i, 64);

    unsigned int hw[5];
#pragma unroll
    for (int i = 0; i < 5; ++i)
        hw[i] = *((const unsigned int*)(emb + (size_t)fx[i] * DD) + c);

    float4v s4 = (float4v)0.0f, ss4 = (float4v)0.0f;
#pragma unroll
    for (int i = 0; i < 5; ++i) {
        float4v g;
        g.x = __builtin_amdgcn_cvt_f32_fp8(hw[i], 0);
        g.y = __builtin_amdgcn_cvt_f32_fp8(hw[i], 1);
        g.z = __builtin_amdgcn_cvt_f32_fp8(hw[i], 2);
        g.w = __builtin_amdgcn_cvt_f32_fp8(hw[i], 3);
        s4 += g; ss4 += g * g;
    }

#pragma unroll
    for (int off = 16; off <= 32; off <<= 1) {
        float4v t, u;
        t.x = __shfl_xor(s4.x,  off, 64); t.y = __shfl_xor(s4.y,  off, 64);
        t.z = __shfl_xor(s4.z,  off, 64); t.w = __shfl_xor(s4.w,  off, 64);
        u.x = __shfl_xor(ss4.x, off, 64); u.y = __shfl_xor(ss4.y, off, 64);
        u.z = __shfl_xor(ss4.z, off, 64); u.w = __shfl_xor(ss4.w, off, 64);
        s4 += t; ss4 += u;
    }

    float part = myw;
    if (grp == 0) {
        float4v h14 = *(const float4v*)(h1 + c * 4);
        float4v bi4 = 0.5f * (s4 * s4 - ss4);
        part += bi4.x*h14.x + bi4.y*h14.y + bi4.z*h14.z + bi4.w*h14.w;
        ushort4v o;
        o.x = f2bf(s4.x); o.y = f2bf(s4.y); o.z = f2bf(s4.z); o.w = f2bf(s4.w);
        *(ushort4v*)(srow + c * 4) = o;
    }

#pragma unroll
    for (int off = 1; off <= 32; off <<= 1)
        part += __shfl_xor(part, off, 64);

    if (lane == 0) *sc = part + extra;
}

// ---------------------------------------------------------------------------
// MFMA Gram partial, LDS-FREE: one wave per 64-row tile stride. G = M^T M,
// so the 16x16x32 A-frag and B-frag of a 16-dim block are the SAME registers:
// lane (q = lane>>4, c = lane&15) holds f[Db][j] = M[row0+kb*32+q*8+j][Db*16+c],
// gathered directly from global (per load instr: 4 rows x 32B contiguous).
// Full 4x4 tile grid of MFMAs -> full 64x64 partial store (keeps the
// downstream reduce fully coalesced). No __shared__ at all on this path.
// C/D layout (m89-verified, r1-passed): col = lane&15, row = (lane>>4)*4+reg.
// ---------------------------------------------------------------------------
__device__ __forceinline__ void gram_block_mfma(
    const unsigned short* __restrict__ M, int nrows, int gwid, int nw,
    float* __restrict__ Gpart)
{
    int lane = threadIdx.x & 63;
    int q = lane >> 4;       // lane quarter -> k-subrange / output row group
    int c = lane & 15;       // dim-within-block -> output col

    float4v acc[4][4];
#pragma unroll
    for (int ti = 0; ti < 4; ++ti)
#pragma unroll
        for (int tj = 0; tj < 4; ++tj)
            acc[ti][tj] = (float4v)0.0f;

    int ntiles = (nrows + 63) >> 6;
    for (int tt = gwid; tt < ntiles; tt += nw) {
        int row0 = tt << 6;
#pragma unroll
        for (int kb = 0; kb < 2; ++kb) {
            int r0 = row0 + kb * 32 + q * 8;
            const unsigned short* base = M + (size_t)r0 * DD + c;
            short8v f[4];
            if (row0 + 64 <= nrows) {
#pragma unroll
                for (int Db = 0; Db < 4; ++Db)
#pragma unroll
                    for (int j = 0; j < 8; ++j)
                        f[Db][j] = (short)base[(size_t)j * DD + Db * 16];
            } else {
#pragma unroll
                for (int Db = 0; Db < 4; ++Db)
#pragma unroll
                    for (int j = 0; j < 8; ++j)
                        f[Db][j] = (r0 + j < nrows)
                                 ? (short)base[(size_t)j * DD + Db * 16]
                                 : (short)0;
            }
#pragma unroll
            for (int ti = 0; ti < 4; ++ti)
#pragma unroll
                for (int tj = 0; tj < 4; ++tj)
                    acc[ti][tj] = __builtin_amdgcn_mfma_f32_16x16x32_bf16(
                        f[ti], f[tj], acc[ti][tj], 0, 0, 0);
        }
    }

    float* out = Gpart + (size_t)gwid * (DD * DD);
#pragma unroll
    for (int ti = 0; ti < 4; ++ti)
#pragma unroll
        for (int tj = 0; tj < 4; ++tj)
#pragma unroll
            for (int rg = 0; rg < 4; ++rg)
                out[(ti * 16 + q * 4 + rg) * DD + tj * 16 + c] = acc[ti][tj][rg];
}

// ---------------------------------------------------------------------------
// Kernel 2 (fused): blocks [0,GAB) Gram-A, [GAB,GAB+GBB) Gram-B,
// [GAB+GBB, +POSB) pos pairs. Gram path uses no LDS -> pos occupancy is
// wave-limited (8 blocks/CU), not LDS-limited.
// ---------------------------------------------------------------------------
__global__ __launch_bounds__(256) void mid_kernel(
    const unsigned short* __restrict__ p_bf, int U, float* __restrict__ PA,
    const unsigned short* __restrict__ q_bf, int V, float* __restrict__ PB,
    const float* __restrict__ su, const float* __restrict__ sv,
    const float* __restrict__ h2,
    const int* __restrict__ pu, const int* __restrict__ pi,
    int P, float* __restrict__ posPart)
{
    __shared__ float red[4];
    int w = threadIdx.x >> 6;

    if (blockIdx.x < GAB) {
        gram_block_mfma(p_bf, U, blockIdx.x * 4 + w, GA, PA);
        return;
    }
    if (blockIdx.x < GAB + GBB) {
        gram_block_mfma(q_bf, V, (blockIdx.x - GAB) * 4 + w, GB, PB);
        return;
    }

    // ---- positive-pair part ----
    int lane = threadIdx.x & 63;
    int sl   = lane & 15;
    int sub  = lane >> 4;
    int pb   = blockIdx.x - (GAB + GBB);
    int wId  = pb * 4 + w;
    const int NW = POSB * 4;                 // 8192 waves

    float4v h2v = *(const float4v*)(h2 + sl * 4);

    int pid0 = wId * 4 + sub;                // [0, 32768)
    int pid1 = pid0 + NW * 4;                // [32768, 65536)
    bool ok0 = pid0 < P, ok1 = pid1 < P;

    int u0 = 0, v0 = 0, u1 = 0, v1 = 0;
    if (ok0) { u0 = pu[pid0]; v0 = pi[pid0]; }
    if (ok1) { u1 = pu[pid1]; v1 = pi[pid1]; }

    ushort4v ph0 = (ushort4v)0, qh0 = (ushort4v)0;
    ushort4v ph1 = (ushort4v)0, qh1 = (ushort4v)0;
    if (ok0) {
        ph0 = *(const ushort4v*)(p_bf + (size_t)u0 * DD + sl * 4);
        qh0 = *(const ushort4v*)(q_bf + (size_t)v0 * DD + sl * 4);
    }
    if (ok1) {
        ph1 = *(const ushort4v*)(p_bf + (size_t)u1 * DD + sl * 4);
        qh1 = *(const ushort4v*)(q_bf + (size_t)v1 * DD + sl * 4);
    }

    float d0 = bf2f(ph0.x)*bf2f(qh0.x)*h2v.x + bf2f(ph0.y)*bf2f(qh0.y)*h2v.y
             + bf2f(ph0.z)*bf2f(qh0.z)*h2v.z + bf2f(ph0.w)*bf2f(qh0.w)*h2v.w;
    float d1 = bf2f(ph1.x)*bf2f(qh1.x)*h2v.x + bf2f(ph1.y)*bf2f(qh1.y)*h2v.y
             + bf2f(ph1.z)*bf2f(qh1.z)*h2v.z + bf2f(ph1.w)*bf2f(qh1.w)*h2v.w;
#pragma unroll
    for (int off = 1; off < 16; off <<= 1) {
        d0 += __shfl_xor(d0, off, 64);
        d1 += __shfl_xor(d1, off, 64);
    }

    float acc = 0.0f;
    if (sl == 0) {
        if (ok0) { float y = d0 + su[u0] + sv[v0]; acc += 0.5f * y * y - 2.0f * y; }
        if (ok1) { float y = d1 + su[u1] + sv[v1]; acc += 0.5f * y * y - 2.0f * y; }
    }
    acc += __shfl_xor(acc, 16, 64);
    acc += __shfl_xor(acc, 32, 64);
    if (lane == 0) red[w] = acc;
    __syncthreads();
    if (threadIdx.x == 0)
        posPart[pb] = red[0] + red[1] + red[2] + red[3];
}

// ---------------------------------------------------------------------------
// Kernel 3: reduce gram partials -> negative term, plus pos partials.
// Partials hold full 64x64 again -> fully coalesced reads (v0 indexing).
// ---------------------------------------------------------------------------
__global__ __launch_bounds__(256) void neg_reduce_kernel(
    const float* __restrict__ PA, const float* __restrict__ PB,
    const float* __restrict__ h2, const float* __restrict__ posPart,
    float* __restrict__ out)
{
    __shared__ float sA[4][64], sB[4][64];
    __shared__ float sPos;
    int t  = threadIdx.x;
    int l  = t & 63;
    int ch = t >> 6;                       // k-chunk 0..3
    int e  = blockIdx.x * 64 + l;          // Gram entry, i=blockIdx.x, j=l

    float a = 0.0f, b = 0.0f;
#pragma unroll
    for (int k = 0; k < GA / 4; ++k)       // 16 coalesced loads
        a += PA[(size_t)(ch * (GA / 4) + k) * (DD * DD) + e];
#pragma unroll
    for (int k = 0; k < GB / 4; ++k)       // 32 coalesced loads
        b += PB[(size_t)(ch * (GB / 4) + k) * (DD * DD) + e];
    sA[ch][l] = a;
    sB[ch][l] = b;

    if (ch == 1) {                         // wave 1: fold 32 pos partials
        float p = (l < POSB / NEGB) ? posPart[blockIdx.x * (POSB / NEGB) + l] : 0.0f;
#pragma unroll
        for (int off = 1; off <= 32; off <<= 1)
            p += __shfl_xor(p, off, 64);
        if (l == 0) sPos = p;
    }
    __syncthreads();

    if (ch == 0) {
        float fa = sA[0][l] + sA[1][l] + sA[2][l] + sA[3][l];
        float fb = sB[0][l] + sB[1][l] + sB[2][l] + sB[3][l];
        float acc = 0.5f * h2[blockIdx.x] * h2[l] * fa * fb;
#pragma unroll
        for (int off = 1; off <= 32; off <<= 1)
            acc += __shfl_xor(acc, off, 64);
        if (l == 0)
            atomicAdd(out, acc + sPos);
    }
}

extern "C" void kernel_launch(void* const* d_in, const int* in_sizes, int n_in,
                              void* d_out, int out_size, void* d_ws, size_t ws_size,
                              hipStream_t stream)
{
    const float* user_emb = (const float*)d_in[0];
    const float* item_emb = (const float*)d_in[1];
    const float* w_user   = (const float*)d_in[2];
    const float* w_item   = (const float*)d_in[3];
    const float* bias     = (const float*)d_in[4];
    const float* h1       = (const float*)d_in[5];
    const float* h2       = (const float*)d_in[6];
    const int*   ufeat    = (const int*)d_in[7];
    const int*   ifeat    = (const int*)d_in[8];
    const int*   pu       = (const int*)d_in[9];
    const int*   pi       = (const int*)d_in[10];

    const int NF = in_sizes[0] / DD;
    const int U  = in_sizes[7] / FD;
    const int V  = in_sizes[8] / FD;
    const int P  = in_sizes[9];

    float* ws = (float*)d_ws;
    size_t off = 0;
    unsigned short* p_bf = (unsigned short*)(ws + off); off += (size_t)U * DD / 2;
    unsigned short* q_bf = (unsigned short*)(ws + off); off += (size_t)V * DD / 2;
    float* su   = ws + off; off += (size_t)U;          off = (off + 63) & ~(size_t)63;
    float* sv   = ws + off; off += (size_t)V;          off = (off + 63) & ~(size_t)63;
    float* PA   = ws + off; off += (size_t)GA * DD * DD;
    float* PB   = ws + off; off += (size_t)GB * DD * DD;
    float* posPart = ws + off; off += (size_t)POSB;    off = (off + 63) & ~(size_t)63;
    unsigned char* uf8 = (unsigned char*)(ws + off);   off += (size_t)NF * DD / 4;
    unsigned char* if8 = (unsigned char*)(ws + off);   off += (size_t)NF * DD / 4;

    float* out = (float*)d_out;

    int n4 = NF * DD / 4;
    conv_kernel<<<(2 * n4 + 255) / 256, 256, 0, stream>>>(
        user_emb, item_emb, (unsigned int*)uf8, (unsigned int*)if8,
        n4, out, out_size);

    int nent = U + V;
    entity_kernel<<<(nent + 3) / 4, 256, 0, stream>>>(
        uf8, if8, w_user, w_item, bias, h1,
        ufeat, ifeat, p_bf, su, q_bf, sv, U, V);

    mid_kernel<<<GAB + GBB + POSB, 256, 0, stream>>>(
        p_bf, U, PA, q_bf, V, PB, su, sv, h2, pu, pi, P, posPart);

    neg_reduce_kernel<<<NEGB, 256, 0, stream>>>(PA, PB, h2, posPart, out);
}

// Round 3
// 144.296 us; speedup vs baseline: 1.1645x; 1.0289x over previous
//
#include <hip/hip_runtime.h>

#define FD 20
#define DD 64

#define GA 64     // gram partials for A (users)  = GAB blocks * 4 waves
#define GB 128    // gram partials for B (items)  = GBB blocks * 4 waves
#define GAB 16    // gram blocks for A
#define GBB 32    // gram blocks for B
#define POSB 2048 // pos blocks in fused mid kernel
#define NEGB 64   // neg reduce blocks (one Gram row each)

typedef float float2v __attribute__((ext_vector_type(2)));
typedef float float4v __attribute__((ext_vector_type(4)));
typedef unsigned short ushort4v __attribute__((ext_vector_type(4)));
typedef unsigned short ushort8v __attribute__((ext_vector_type(8)));
typedef short short8v __attribute__((ext_vector_type(8)));

__device__ __forceinline__ unsigned short f2bf(float f) {
    unsigned u = __float_as_uint(f);
    unsigned r = u + 0x7fffu + ((u >> 16) & 1u);   // round-to-nearest-even
    return (unsigned short)(r >> 16);
}
__device__ __forceinline__ float bf2f(unsigned short h) {
    return __uint_as_float((unsigned)h << 16);
}

// ---------------------------------------------------------------------------
// Kernel 0: fp32 -> fp8 e4m3 (OCP) conversion of both embedding tables via
// HW v_cvt_pk_fp8_f32, plus zero-init of d_out.
// ---------------------------------------------------------------------------
__global__ __launch_bounds__(256) void conv_kernel(
    const float* __restrict__ ue, const float* __restrict__ ie,
    unsigned int* __restrict__ u8, unsigned int* __restrict__ i8,
    int n4, float* __restrict__ out, int out_size)
{
    int i = blockIdx.x * blockDim.x + threadIdx.x;
    if (i < out_size) out[i] = 0.0f;
    if (i >= 2 * n4) return;
    const float4v* src; unsigned int* dst; int k;
    if (i < n4) { src = (const float4v*)ue; dst = u8; k = i; }
    else        { src = (const float4v*)ie; dst = i8; k = i - n4; }
    float4v v = src[k];
    unsigned int p = 0;
    p = __builtin_amdgcn_cvt_pk_fp8_f32(v.x, v.y, p, false);  // bytes 0,1
    p = __builtin_amdgcn_cvt_pk_fp8_f32(v.z, v.w, p, true);   // bytes 2,3
    dst[k] = p;
}

// ---------------------------------------------------------------------------
// Kernel 1 (rewritten): 4 entities per wave, 16 lanes each. Lane (e,c)
// owns dims [4c,4c+4) of entity e across ALL 20 features:
//   - s/ss accumulation is lane-local (NO cross-lane reduction)
//   - packed v_cvt_pk_f32_fp8 decode (2 fp8 -> float2 per op)
//   - 20 independent 4B gathers in flight per lane (4x old MLP)
// Per load instr the wave still reads 4 rows x 64B contiguous segments.
// Only the scalar (bi.h1 + w-sum) needs a 16-lane shfl reduce.
// ---------------------------------------------------------------------------
__global__ __launch_bounds__(256, 4) void entity_kernel(
    const unsigned char* __restrict__ user_f8,
    const unsigned char* __restrict__ item_f8,
    const float* __restrict__ w_user, const float* __restrict__ w_item,
    const float* __restrict__ bias, const float* __restrict__ h1,
    const int* __restrict__ ufeat, const int* __restrict__ ifeat,
    unsigned short* __restrict__ p_bf, float* __restrict__ su,
    unsigned short* __restrict__ q_bf, float* __restrict__ sv,
    int U, int V)
{
    int gwid = (int)((blockIdx.x * blockDim.x + threadIdx.x) >> 6);
    int lane = threadIdx.x & 63;
    int eg   = lane >> 4;            // entity slot within wave: 0..3
    int c    = lane & 15;            // dim chunk (4 dims)
    int ent  = gwid * 4 + eg;
    if (ent >= U + V) return;

    bool isU = ent < U;
    int  m   = isU ? ent : ent - U;
    const unsigned char* emb = isU ? user_f8 : item_f8;
    const float* wv   = isU ? w_user : w_item;
    const int*   fidx = (isU ? ufeat : ifeat) + (size_t)m * FD;
    float extra       = isU ? bias[0] : 0.0f;
    unsigned short* srow = (isU ? p_bf : q_bf) + (size_t)m * DD;
    float* sc         = (isU ? su : sv) + m;

    // 20 feature indices (uniform within the 16-lane group; L1-hot)
    int idx[FD];
#pragma unroll
    for (int j = 0; j < FD; ++j) idx[j] = fidx[j];

    // 20 independent 4B gathers, all in flight
    unsigned int hw[FD];
#pragma unroll
    for (int j = 0; j < FD; ++j)
        hw[j] = *((const unsigned int*)(emb + (size_t)idx[j] * DD) + c);

    float4v s4 = (float4v)0.0f, ss4 = (float4v)0.0f;
#pragma unroll
    for (int j = 0; j < FD; ++j) {
        float2v lo = __builtin_amdgcn_cvt_pk_f32_fp8(hw[j], false);
        float2v hi = __builtin_amdgcn_cvt_pk_f32_fp8(hw[j], true);
        float4v g;
        g.x = lo.x; g.y = lo.y; g.z = hi.x; g.w = hi.y;
        s4 += g; ss4 += g * g;
    }

    // first-order w sum: lane c covers j=c, lanes 0..3 also j=16+c
    float part = wv[idx[c]];
    if (c < FD - 16) part += wv[idx[16 + c]];

    // bi-interaction dot h1 (lane-local 4 dims)
    float4v h14 = *(const float4v*)(h1 + c * 4);
    float4v bi4 = 0.5f * (s4 * s4 - ss4);
    part += bi4.x*h14.x + bi4.y*h14.y + bi4.z*h14.z + bi4.w*h14.w;

    // 16-lane group reduce (stays within the entity's lane group)
#pragma unroll
    for (int off = 1; off <= 8; off <<= 1)
        part += __shfl_xor(part, off, 64);

    // bf16 row store: 64 lanes -> 4 rows x 128B
    ushort4v o;
    o.x = f2bf(s4.x); o.y = f2bf(s4.y); o.z = f2bf(s4.z); o.w = f2bf(s4.w);
    *(ushort4v*)(srow + c * 4) = o;

    if (c == 0) *sc = part + extra;
}

// ---------------------------------------------------------------------------
// MFMA Gram partial, LDS-FREE (unchanged from r2): one wave per 64-row tile
// stride; A-frag == B-frag; full 4x4 MFMA grid; full 64x64 partial store.
// C/D layout (m89-verified, r1/r2-passed): col = lane&15, row = (lane>>4)*4+reg.
// ---------------------------------------------------------------------------
__device__ __forceinline__ void gram_block_mfma(
    const unsigned short* __restrict__ M, int nrows, int gwid, int nw,
    float* __restrict__ Gpart)
{
    int lane = threadIdx.x & 63;
    int q = lane >> 4;
    int c = lane & 15;

    float4v acc[4][4];
#pragma unroll
    for (int ti = 0; ti < 4; ++ti)
#pragma unroll
        for (int tj = 0; tj < 4; ++tj)
            acc[ti][tj] = (float4v)0.0f;

    int ntiles = (nrows + 63) >> 6;
    for (int tt = gwid; tt < ntiles; tt += nw) {
        int row0 = tt << 6;
#pragma unroll
        for (int kb = 0; kb < 2; ++kb) {
            int r0 = row0 + kb * 32 + q * 8;
            const unsigned short* base = M + (size_t)r0 * DD + c;
            short8v f[4];
            if (row0 + 64 <= nrows) {
#pragma unroll
                for (int Db = 0; Db < 4; ++Db)
#pragma unroll
                    for (int j = 0; j < 8; ++j)
                        f[Db][j] = (short)base[(size_t)j * DD + Db * 16];
            } else {
#pragma unroll
                for (int Db = 0; Db < 4; ++Db)
#pragma unroll
                    for (int j = 0; j < 8; ++j)
                        f[Db][j] = (r0 + j < nrows)
                                 ? (short)base[(size_t)j * DD + Db * 16]
                                 : (short)0;
            }
#pragma unroll
            for (int ti = 0; ti < 4; ++ti)
#pragma unroll
                for (int tj = 0; tj < 4; ++tj)
                    acc[ti][tj] = __builtin_amdgcn_mfma_f32_16x16x32_bf16(
                        f[ti], f[tj], acc[ti][tj], 0, 0, 0);
        }
    }

    float* out = Gpart + (size_t)gwid * (DD * DD);
#pragma unroll
    for (int ti = 0; ti < 4; ++ti)
#pragma unroll
        for (int tj = 0; tj < 4; ++tj)
#pragma unroll
            for (int rg = 0; rg < 4; ++rg)
                out[(ti * 16 + q * 4 + rg) * DD + tj * 16 + c] = acc[ti][tj][rg];
}

// ---------------------------------------------------------------------------
// Kernel 2 (fused, unchanged from r2)
// ---------------------------------------------------------------------------
__global__ __launch_bounds__(256) void mid_kernel(
    const unsigned short* __restrict__ p_bf, int U, float* __restrict__ PA,
    const unsigned short* __restrict__ q_bf, int V, float* __restrict__ PB,
    const float* __restrict__ su, const float* __restrict__ sv,
    const float* __restrict__ h2,
    const int* __restrict__ pu, const int* __restrict__ pi,
    int P, float* __restrict__ posPart)
{
    __shared__ float red[4];
    int w = threadIdx.x >> 6;

    if (blockIdx.x < GAB) {
        gram_block_mfma(p_bf, U, blockIdx.x * 4 + w, GA, PA);
        return;
    }
    if (blockIdx.x < GAB + GBB) {
        gram_block_mfma(q_bf, V, (blockIdx.x - GAB) * 4 + w, GB, PB);
        return;
    }

    // ---- positive-pair part ----
    int lane = threadIdx.x & 63;
    int sl   = lane & 15;
    int sub  = lane >> 4;
    int pb   = blockIdx.x - (GAB + GBB);
    int wId  = pb * 4 + w;
    const int NW = POSB * 4;                 // 8192 waves

    float4v h2v = *(const float4v*)(h2 + sl * 4);

    int pid0 = wId * 4 + sub;                // [0, 32768)
    int pid1 = pid0 + NW * 4;                // [32768, 65536)
    bool ok0 = pid0 < P, ok1 = pid1 < P;

    int u0 = 0, v0 = 0, u1 = 0, v1 = 0;
    if (ok0) { u0 = pu[pid0]; v0 = pi[pid0]; }
    if (ok1) { u1 = pu[pid1]; v1 = pi[pid1]; }

    ushort4v ph0 = (ushort4v)0, qh0 = (ushort4v)0;
    ushort4v ph1 = (ushort4v)0, qh1 = (ushort4v)0;
    if (ok0) {
        ph0 = *(const ushort4v*)(p_bf + (size_t)u0 * DD + sl * 4);
        qh0 = *(const ushort4v*)(q_bf + (size_t)v0 * DD + sl * 4);
    }
    if (ok1) {
        ph1 = *(const ushort4v*)(p_bf + (size_t)u1 * DD + sl * 4);
        qh1 = *(const ushort4v*)(q_bf + (size_t)v1 * DD + sl * 4);
    }

    float d0 = bf2f(ph0.x)*bf2f(qh0.x)*h2v.x + bf2f(ph0.y)*bf2f(qh0.y)*h2v.y
             + bf2f(ph0.z)*bf2f(qh0.z)*h2v.z + bf2f(ph0.w)*bf2f(qh0.w)*h2v.w;
    float d1 = bf2f(ph1.x)*bf2f(qh1.x)*h2v.x + bf2f(ph1.y)*bf2f(qh1.y)*h2v.y
             + bf2f(ph1.z)*bf2f(qh1.z)*h2v.z + bf2f(ph1.w)*bf2f(qh1.w)*h2v.w;
#pragma unroll
    for (int off = 1; off < 16; off <<= 1) {
        d0 += __shfl_xor(d0, off, 64);
        d1 += __shfl_xor(d1, off, 64);
    }

    float acc = 0.0f;
    if (sl == 0) {
        if (ok0) { float y = d0 + su[u0] + sv[v0]; acc += 0.5f * y * y - 2.0f * y; }
        if (ok1) { float y = d1 + su[u1] + sv[v1]; acc += 0.5f * y * y - 2.0f * y; }
    }
    acc += __shfl_xor(acc, 16, 64);
    acc += __shfl_xor(acc, 32, 64);
    if (lane == 0) red[w] = acc;
    __syncthreads();
    if (threadIdx.x == 0)
        posPart[pb] = red[0] + red[1] + red[2] + red[3];
}

// ---------------------------------------------------------------------------
// Kernel 3 (unchanged from r2)
// ---------------------------------------------------------------------------
__global__ __launch_bounds__(256) void neg_reduce_kernel(
    const float* __restrict__ PA, const float* __restrict__ PB,
    const float* __restrict__ h2, const float* __restrict__ posPart,
    float* __restrict__ out)
{
    __shared__ float sA[4][64], sB[4][64];
    __shared__ float sPos;
    int t  = threadIdx.x;
    int l  = t & 63;
    int ch = t >> 6;                       // k-chunk 0..3
    int e  = blockIdx.x * 64 + l;          // Gram entry, i=blockIdx.x, j=l

    float a = 0.0f, b = 0.0f;
#pragma unroll
    for (int k = 0; k < GA / 4; ++k)       // 16 coalesced loads
        a += PA[(size_t)(ch * (GA / 4) + k) * (DD * DD) + e];
#pragma unroll
    for (int k = 0; k < GB / 4; ++k)       // 32 coalesced loads
        b += PB[(size_t)(ch * (GB / 4) + k) * (DD * DD) + e];
    sA[ch][l] = a;
    sB[ch][l] = b;

    if (ch == 1) {                         // wave 1: fold 32 pos partials
        float p = (l < POSB / NEGB) ? posPart[blockIdx.x * (POSB / NEGB) + l] : 0.0f;
#pragma unroll
        for (int off = 1; off <= 32; off <<= 1)
            p += __shfl_xor(p, off, 64);
        if (l == 0) sPos = p;
    }
    __syncthreads();

    if (ch == 0) {
        float fa = sA[0][l] + sA[1][l] + sA[2][l] + sA[3][l];
        float fb = sB[0][l] + sB[1][l] + sB[2][l] + sB[3][l];
        float acc = 0.5f * h2[blockIdx.x] * h2[l] * fa * fb;
#pragma unroll
        for (int off = 1; off <= 32; off <<= 1)
            acc += __shfl_xor(acc, off, 64);
        if (l == 0)
            atomicAdd(out, acc + sPos);
    }
}

extern "C" void kernel_launch(void* const* d_in, const int* in_sizes, int n_in,
                              void* d_out, int out_size, void* d_ws, size_t ws_size,
                              hipStream_t stream)
{
    const float* user_emb = (const float*)d_in[0];
    const float* item_emb = (const float*)d_in[1];
    const float* w_user   = (const float*)d_in[2];
    const float* w_item   = (const float*)d_in[3];
    const float* bias     = (const float*)d_in[4];
    const float* h1       = (const float*)d_in[5];
    const float* h2       = (const float*)d_in[6];
    const int*   ufeat    = (const int*)d_in[7];
    const int*   ifeat    = (const int*)d_in[8];
    const int*   pu       = (const int*)d_in[9];
    const int*   pi       = (const int*)d_in[10];

    const int NF = in_sizes[0] / DD;
    const int U  = in_sizes[7] / FD;
    const int V  = in_sizes[8] / FD;
    const int P  = in_sizes[9];

    float* ws = (float*)d_ws;
    size_t off = 0;
    unsigned short* p_bf = (unsigned short*)(ws + off); off += (size_t)U * DD / 2;
    unsigned short* q_bf = (unsigned short*)(ws + off); off += (size_t)V * DD / 2;
    float* su   = ws + off; off += (size_t)U;          off = (off + 63) & ~(size_t)63;
    float* sv   = ws + off; off += (size_t)V;          off = (off + 63) & ~(size_t)63;
    float* PA   = ws + off; off += (size_t)GA * DD * DD;
    float* PB   = ws + off; off += (size_t)GB * DD * DD;
    float* posPart = ws + off; off += (size_t)POSB;    off = (off + 63) & ~(size_t)63;
    unsigned char* uf8 = (unsigned char*)(ws + off);   off += (size_t)NF * DD / 4;
    unsigned char* if8 = (unsigned char*)(ws + off);   off += (size_t)NF * DD / 4;

    float* out = (float*)d_out;

    int n4 = NF * DD / 4;
    conv_kernel<<<(2 * n4 + 255) / 256, 256, 0, stream>>>(
        user_emb, item_emb, (unsigned int*)uf8, (unsigned int*)if8,
        n4, out, out_size);

    int nent = U + V;
    int nwaves = (nent + 3) / 4;             // 4 entities per wave
    entity_kernel<<<(nwaves + 3) / 4, 256, 0, stream>>>(
        uf8, if8, w_user, w_item, bias, h1,
        ufeat, ifeat, p_bf, su, q_bf, sv, U, V);

    mid_kernel<<<GAB + GBB + POSB, 256, 0, stream>>>(
        p_bf, U, PA, q_bf, V, PB, su, sv, h2, pu, pi, P, posPart);

    neg_reduce_kernel<<<NEGB, 256, 0, stream>>>(PA, PB, h2, posPart, out);
}